// Round 1
// baseline (625.738 us; speedup 1.0000x reference)
//
#include <hip/hip_runtime.h>
#include <math.h>

#define BB 64
#define HH 1024
#define VV 32000
#define SRC 128

__device__ __forceinline__ float sigmoidf_(float x){ return 1.f/(1.f+expf(-x)); }

// ---------------- GEMM: C[64,N] = A[64,K] @ B^T (+bias)(+tanh) ----------------
// B is row-major [N,K] split into two weight arrays at K0 (for [W_ih|W_hh]).
// EPI: 0 = raw, 1 = +bias, 2 = +bias then tanh
template<int EPI>
__global__ __launch_bounds__(256)
void gemm64(const float* __restrict__ A, int lda,
            const float* __restrict__ B0, int ldb0,
            const float* __restrict__ B1, int ldb1, int K0,
            int K, int N,
            const float* __restrict__ bias,
            float* __restrict__ C)
{
    __shared__ float As[32][68];   // [kk][m], pad 68 for bank spread, 16B-aligned rows
    __shared__ float Bs[32][68];
    const int tid = threadIdx.x;
    const int n0 = blockIdx.x * 64;
    const int ty = tid >> 4, tx = tid & 15;
    float acc[4][4] = {{0.f,0.f,0.f,0.f},{0.f,0.f,0.f,0.f},
                       {0.f,0.f,0.f,0.f},{0.f,0.f,0.f,0.f}};
    for (int k0 = 0; k0 < K; k0 += 32) {
        const float* Bp; int ldb, kb;
        if (k0 < K0) { Bp = B0; ldb = ldb0; kb = k0; }
        else         { Bp = B1; ldb = ldb1; kb = k0 - K0; }
        #pragma unroll
        for (int r = 0; r < 8; ++r) {
            int e  = tid + 256*r;     // 0..2047
            int m  = e >> 5, kk = e & 31;
            As[kk][m] = A[m*lda + k0 + kk];
            Bs[kk][m] = Bp[(size_t)(n0+m)*ldb + kb + kk];
        }
        __syncthreads();
        #pragma unroll
        for (int kk = 0; kk < 32; ++kk) {
            float4 a4 = *(const float4*)&As[kk][ty<<2];
            float4 b4 = *(const float4*)&Bs[kk][tx<<2];
            float av[4] = {a4.x,a4.y,a4.z,a4.w};
            float bv[4] = {b4.x,b4.y,b4.z,b4.w};
            #pragma unroll
            for (int i=0;i<4;++i)
                #pragma unroll
                for (int j=0;j<4;++j)
                    acc[i][j] = fmaf(av[i], bv[j], acc[i][j]);
        }
        __syncthreads();
    }
    #pragma unroll
    for (int i=0;i<4;++i) {
        int m = (ty<<2) + i;
        float4 o;
        float* op = &o.x;
        #pragma unroll
        for (int j=0;j<4;++j) {
            int n = n0 + (tx<<2) + j;
            float v = acc[i][j];
            if (EPI >= 1) v += bias[n];
            if (EPI == 2) v = tanhf(v);
            op[j] = v;
        }
        *(float4*)&C[(size_t)m*N + n0 + (tx<<2)] = o;
    }
}

// ---------------- embedding gather + A_cat prep ----------------
__global__ __launch_bounds__(256)
void prep_kernel(const int* __restrict__ tokens, const float* __restrict__ emb,
                 const float* __restrict__ h0,
                 float* __restrict__ Acat0, float* __restrict__ Acat1)
{
    int idx = blockIdx.x*256 + threadIdx.x;     // 0..65535
    int b = idx >> 10, k = idx & 1023;
    int tok = tokens[b];
    Acat0[b*2048 + k]        = emb[(size_t)tok*HH + k];
    Acat0[b*2048 + 1024 + k] = h0[b*HH + k];                 // h0[0]
    Acat1[b*2048 + 1024 + k] = h0[BB*HH + b*HH + k];         // h0[1]
}

// ---------------- LSTM pointwise ----------------
__global__ __launch_bounds__(256)
void lstm_point(const float* __restrict__ gates,
                const float* __restrict__ bih, const float* __restrict__ bhh,
                const float* __restrict__ c0,
                float* __restrict__ hn, float* __restrict__ cn,
                float* __restrict__ hA, int hAoff)
{
    int idx = blockIdx.x*256 + threadIdx.x;     // 0..65535
    int b = idx >> 10, k = idx & 1023;
    const float* g = gates + b*4096;
    float ig = g[k]        + bih[k]        + bhh[k];
    float fg = g[1024 + k] + bih[1024 + k] + bhh[1024 + k];
    float gg = g[2048 + k] + bih[2048 + k] + bhh[2048 + k];
    float og = g[3072 + k] + bih[3072 + k] + bhh[3072 + k];
    float c = sigmoidf_(fg)*c0[b*HH + k] + sigmoidf_(ig)*tanhf(gg);
    float h = sigmoidf_(og)*tanhf(c);
    cn[b*HH + k] = c;
    hn[b*HH + k] = h;
    hA[b*2048 + hAoff + k] = h;
}

// ---------------- attention: u = attn_W^T v ; c_s = v . attn_b ----------------
__global__ __launch_bounds__(256)
void attn_u_kernel(const float* __restrict__ attn_W, const float* __restrict__ attn_v,
                   const float* __restrict__ attn_b,
                   float* __restrict__ u, float* __restrict__ c_s)
{
    if (blockIdx.x < 8) {
        int k = blockIdx.x*256 + threadIdx.x;   // 0..2047
        float s = 0.f;
        for (int h = 0; h < HH; ++h) s = fmaf(attn_v[h], attn_W[(size_t)h*2048 + k], s);
        u[k] = s;
    } else {
        __shared__ float red[256];
        float s = 0.f;
        for (int h = threadIdx.x; h < HH; h += 256) s = fmaf(attn_v[h], attn_b[h], s);
        red[threadIdx.x] = s; __syncthreads();
        for (int o = 128; o > 0; o >>= 1) {
            if (threadIdx.x < o) red[threadIdx.x] += red[threadIdx.x + o];
            __syncthreads();
        }
        if (threadIdx.x == 0) *c_s = red[0];
    }
}

// ---------------- d_h[b] = u_h . h_top[b] ----------------
__global__ __launch_bounds__(256)
void dh_kernel(const float* __restrict__ u, const float* __restrict__ Acat3,
               float* __restrict__ d_h)
{
    int b = blockIdx.x;
    __shared__ float red[256];
    float s = 0.f;
    for (int k = threadIdx.x; k < HH; k += 256)
        s = fmaf(u[k], Acat3[b*2048 + 1024 + k], s);
    red[threadIdx.x] = s; __syncthreads();
    for (int o = 128; o > 0; o >>= 1) {
        if (threadIdx.x < o) red[threadIdx.x] += red[threadIdx.x + o];
        __syncthreads();
    }
    if (threadIdx.x == 0) d_h[b] = red[0];
}

// ---------------- scores[b,l] = u_e . enc[l,b,:] + d_h[b] + c_s ----------------
__global__ __launch_bounds__(256)
void scores_kernel(const float* __restrict__ u, const float* __restrict__ enc,
                   const float* __restrict__ d_h, const float* __restrict__ c_s,
                   float* __restrict__ scores)
{
    int w    = blockIdx.x*4 + (threadIdx.x >> 6);   // 0..8191
    int lane = threadIdx.x & 63;
    int b = w >> 7, l = w & 127;
    const float* e = enc + (size_t)(l*BB + b)*HH;
    const float* ue = u + 1024;
    float s = 0.f;
    #pragma unroll
    for (int t = 0; t < 16; ++t)
        s = fmaf(ue[lane + 64*t], e[lane + 64*t], s);
    #pragma unroll
    for (int o = 32; o > 0; o >>= 1) s += __shfl_xor(s, o);
    if (lane == 0) scores[b*SRC + l] = s + d_h[b] + *c_s;
}

// ---------------- softmax over l (128) per b ----------------
__global__ __launch_bounds__(64)
void softmax_kernel(const float* __restrict__ scores, float* __restrict__ w)
{
    int b = blockIdx.x, lane = threadIdx.x;
    float s0 = scores[b*SRC + lane], s1 = scores[b*SRC + 64 + lane];
    float m = fmaxf(s0, s1);
    #pragma unroll
    for (int o = 32; o > 0; o >>= 1) m = fmaxf(m, __shfl_xor(m, o));
    float e0 = expf(s0 - m), e1 = expf(s1 - m);
    float sum = e0 + e1;
    #pragma unroll
    for (int o = 32; o > 0; o >>= 1) sum += __shfl_xor(sum, o);
    float inv = 1.f / sum;
    w[b*SRC + lane]      = e0 * inv;
    w[b*SRC + 64 + lane] = e1 * inv;
}

// ---------------- context[b,h] = sum_l w[b,l] enc[l,b,h] ----------------
__global__ __launch_bounds__(256)
void context_kernel(const float* __restrict__ w, const float* __restrict__ enc,
                    float* __restrict__ Acat3)
{
    int idx = blockIdx.x*256 + threadIdx.x;     // 0..65535
    int b = idx >> 10, h = idx & 1023;
    float s = 0.f;
    #pragma unroll 4
    for (int l = 0; l < SRC; ++l)
        s = fmaf(w[b*SRC + l], enc[(size_t)(l*BB + b)*HH + h], s);
    Acat3[b*2048 + h] = s;
}

// ---------------- log-sum-exp per row of logits ----------------
__global__ __launch_bounds__(256)
void lse_kernel(const float* __restrict__ logits, float* __restrict__ lse)
{
    int b = blockIdx.x;
    __shared__ float red[256];
    const float* row = logits + (size_t)b*VV;
    float m = -INFINITY;
    for (int v = threadIdx.x; v < VV; v += 256) m = fmaxf(m, row[v]);
    red[threadIdx.x] = m; __syncthreads();
    for (int o = 128; o > 0; o >>= 1) {
        if (threadIdx.x < o) red[threadIdx.x] = fmaxf(red[threadIdx.x], red[threadIdx.x + o]);
        __syncthreads();
    }
    m = red[0]; __syncthreads();
    float s = 0.f;
    for (int v = threadIdx.x; v < VV; v += 256) s += expf(row[v] - m);
    red[threadIdx.x] = s; __syncthreads();
    for (int o = 128; o > 0; o >>= 1) {
        if (threadIdx.x < o) red[threadIdx.x] += red[threadIdx.x + o];
        __syncthreads();
    }
    if (threadIdx.x == 0) lse[b] = m + logf(red[0]);
}

__global__ __launch_bounds__(256)
void sub_kernel(float* __restrict__ logp, const float* __restrict__ lse)
{
    int v = blockIdx.x*256 + threadIdx.x;       // 0..31999 (125 blocks exact)
    int b = blockIdx.y;
    logp[(size_t)b*VV + v] -= lse[b];
}

// ================================================================
extern "C" void kernel_launch(void* const* d_in, const int* in_sizes, int n_in,
                              void* d_out, int out_size, void* d_ws, size_t ws_size,
                              hipStream_t stream)
{
    const int*   tokens   = (const int*)  d_in[0];
    const float* h0       = (const float*)d_in[1];
    const float* c0       = (const float*)d_in[2];
    const float* enc      = (const float*)d_in[3];
    const float* emb      = (const float*)d_in[4];
    const float* W_ih     = (const float*)d_in[5];
    const float* W_hh     = (const float*)d_in[6];
    const float* b_ih     = (const float*)d_in[7];
    const float* b_hh     = (const float*)d_in[8];
    const float* attn_W   = (const float*)d_in[9];
    const float* attn_b   = (const float*)d_in[10];
    const float* attn_v   = (const float*)d_in[11];
    const float* concat_W = (const float*)d_in[12];
    const float* concat_b = (const float*)d_in[13];
    const float* out_W    = (const float*)d_in[14];
    const float* out_b    = (const float*)d_in[15];

    float* out  = (float*)d_out;
    float* logp = out;                      // [64, 32000]
    float* h_n  = out + (size_t)BB*VV;      // [2, 64, 1024]
    float* c_n  = h_n + 2*BB*HH;            // [2, 64, 1024]

    // workspace layout (floats)
    float* ws     = (float*)d_ws;
    float* Acat0  = ws;                 // [64, 2048]  = [emb ; h0[0]]
    float* Acat1  = Acat0 + 131072;     // [64, 2048]  = [h1 ; h0[1]]
    float* Acat3  = Acat1 + 131072;     // [64, 2048]  = [context ; h_top]
    float* gates  = Acat3 + 131072;     // [64, 4096]
    float* h_c    = gates + 262144;     // [64, 1024]
    float* u      = h_c   + 65536;      // [2048]
    float* c_s    = u     + 2048;       // [1]
    float* d_h    = c_s   + 4;          // [64]
    float* scores = d_h   + 64;         // [64, 128]
    float* attw   = scores+ 8192;       // [64, 128]
    float* lse    = attw  + 8192;       // [64]

    // 1) embedding gather + A_cat prep
    prep_kernel<<<256, 256, 0, stream>>>(tokens, emb, h0, Acat0, Acat1);

    // 2) LSTM layer 0: gates = Acat0 @ [W_ih0 | W_hh0]^T
    gemm64<0><<<64, 256, 0, stream>>>(Acat0, 2048,
                                      W_ih, 1024, W_hh, 1024, 1024,
                                      2048, 4096, nullptr, gates);
    lstm_point<<<256, 256, 0, stream>>>(gates, b_ih, b_hh, c0,
                                        h_n, c_n, Acat1, 0);

    // 3) LSTM layer 1
    gemm64<0><<<64, 256, 0, stream>>>(Acat1, 2048,
                                      W_ih + (size_t)4096*1024, 1024,
                                      W_hh + (size_t)4096*1024, 1024, 1024,
                                      2048, 4096, nullptr, gates);
    lstm_point<<<256, 256, 0, stream>>>(gates, b_ih + 4096, b_hh + 4096, c0 + BB*HH,
                                        h_n + BB*HH, c_n + BB*HH, Acat3, 1024);

    // 4) attention folded vector u = attn_W^T v, scalar c_s = v.b
    attn_u_kernel<<<9, 256, 0, stream>>>(attn_W, attn_v, attn_b, u, c_s);

    // 5) d_h[b] = u_h . h_top[b]
    dh_kernel<<<64, 256, 0, stream>>>(u, Acat3, d_h);

    // 6) scores + softmax + context
    scores_kernel<<<2048, 256, 0, stream>>>(u, enc, d_h, c_s, scores);
    softmax_kernel<<<64, 64, 0, stream>>>(scores, attw);
    context_kernel<<<256, 256, 0, stream>>>(attw, enc, Acat3);

    // 7) concat_out = tanh(Acat3 @ concat_W^T + b)
    gemm64<2><<<16, 256, 0, stream>>>(Acat3, 2048,
                                      concat_W, 2048, nullptr, 0, 2048,
                                      2048, 1024, concat_b, h_c);

    // 8) logits = h_c @ out_W^T + out_b  (written straight into d_out)
    gemm64<1><<<500, 256, 0, stream>>>(h_c, 1024,
                                       out_W, 1024, nullptr, 0, 1024,
                                       1024, VV, out_b, logp);

    // 9) log-softmax
    lse_kernel<<<64, 256, 0, stream>>>(logp, lse);
    sub_kernel<<<dim3(125, 64), 256, 0, stream>>>(logp, lse);
}

// Round 2
// 263.087 us; speedup vs baseline: 2.3784x; 2.3784x over previous
//
#include <hip/hip_runtime.h>
#include <math.h>

#define BB 64
#define HH 1024
#define VV 32000
#define SRC 128

__device__ __forceinline__ float sigmoidf_(float x){ return 1.f/(1.f+expf(-x)); }

// ---------------- GEMM: C[64,N] = A[64,K] @ B^T, split-K capable ----------------
// B row-major [N,K] split into two arrays at global-k K0 (for [W_ih|W_hh]).
// grid.x = N/64 (n-tiles), grid.y = S (k-slices of kChunk each; kChunk % 32 == 0,
// K0 % kChunk == 0 so a slice never straddles B0/B1).
// EPI: 0 = raw partial write to C + blockIdx.y*64*N ; 1 = +bias direct (S must be 1)
template<int EPI>
__global__ __launch_bounds__(256)
void gemm_sk(const float* __restrict__ A, int lda,
             const float* __restrict__ B0, const float* __restrict__ B1,
             int K0, int ldb,
             int kChunk, int N,
             const float* __restrict__ bias,
             float* __restrict__ C)
{
    __shared__ float As[32][68];   // [kk][m]; 68 keeps float4 alignment + bank spread
    __shared__ float Bs[32][68];
    const int tid = threadIdx.x;
    const int n0 = blockIdx.x * 64;
    const int kbase = blockIdx.y * kChunk;
    const int ty = tid >> 4, tx = tid & 15;
    const int nk = kChunk >> 5;

    float acc[4][4];
    #pragma unroll
    for (int i=0;i<4;++i)
        #pragma unroll
        for (int j=0;j<4;++j) acc[i][j] = 0.f;

    float4 aCur[2], bCur[2], aNxt[2], bNxt[2];

    auto loadTile = [&](int t, float4* ar, float4* br) {
        int k0 = kbase + (t << 5);
        const float* Bp; int kb;
        if (k0 < K0) { Bp = B0; kb = k0; } else { Bp = B1; kb = k0 - K0; }
        #pragma unroll
        for (int r = 0; r < 2; ++r) {
            int e = tid + (r << 8);
            int row = e >> 3, kq = e & 7;
            ar[r] = *(const float4*)&A[(size_t)row*lda + k0 + (kq<<2)];
            br[r] = *(const float4*)&Bp[(size_t)(n0+row)*ldb + kb + (kq<<2)];
        }
    };
    auto writeTile = [&](float4* ar, float4* br) {
        #pragma unroll
        for (int r = 0; r < 2; ++r) {
            int e = tid + (r << 8);
            int row = e >> 3, kq = e & 7;
            const float* a = &ar[r].x;
            const float* b = &br[r].x;
            #pragma unroll
            for (int j = 0; j < 4; ++j) {
                As[(kq<<2)+j][row] = a[j];
                Bs[(kq<<2)+j][row] = b[j];
            }
        }
    };

    loadTile(0, aCur, bCur);
    writeTile(aCur, bCur);
    __syncthreads();

    for (int t = 0; t < nk; ++t) {
        if (t + 1 < nk) loadTile(t + 1, aNxt, bNxt);   // overlap with compute below
        #pragma unroll
        for (int kk = 0; kk < 32; ++kk) {
            float4 a4 = *(const float4*)&As[kk][ty<<2];
            float4 b4 = *(const float4*)&Bs[kk][tx<<2];
            float av[4] = {a4.x,a4.y,a4.z,a4.w};
            float bv[4] = {b4.x,b4.y,b4.z,b4.w};
            #pragma unroll
            for (int i=0;i<4;++i)
                #pragma unroll
                for (int j=0;j<4;++j)
                    acc[i][j] = fmaf(av[i], bv[j], acc[i][j]);
        }
        __syncthreads();
        if (t + 1 < nk) {
            writeTile(aNxt, bNxt);
            __syncthreads();
        }
    }

    float* Cp = (EPI == 0) ? (C + (size_t)blockIdx.y * 64 * N) : C;
    #pragma unroll
    for (int i=0;i<4;++i) {
        int m = (ty<<2) + i;
        float4 o;
        float* op = &o.x;
        #pragma unroll
        for (int j=0;j<4;++j) {
            float v = acc[i][j];
            if (EPI == 1) v += bias[n0 + (tx<<2) + j];
            op[j] = v;
        }
        *(float4*)&Cp[(size_t)m*N + n0 + (tx<<2)] = o;
    }
}

// ---------------- embedding gather + A_cat prep ----------------
__global__ __launch_bounds__(256)
void prep_kernel(const int* __restrict__ tokens, const float* __restrict__ emb,
                 const float* __restrict__ h0,
                 float* __restrict__ Acat0, float* __restrict__ Acat1)
{
    int idx = blockIdx.x*256 + threadIdx.x;     // 0..65535
    int b = idx >> 10, k = idx & 1023;
    int tok = tokens[b];
    Acat0[b*2048 + k]        = emb[(size_t)tok*HH + k];
    Acat0[b*2048 + 1024 + k] = h0[b*HH + k];                 // h0[0]
    Acat1[b*2048 + 1024 + k] = h0[BB*HH + b*HH + k];         // h0[1]
}

// ---------------- LSTM pointwise (sums SLSTM=4 split-K partials) ----------------
#define SLSTM 4
__global__ __launch_bounds__(256)
void lstm_point(const float* __restrict__ gates,   // [SLSTM][64][4096]
                const float* __restrict__ bih, const float* __restrict__ bhh,
                const float* __restrict__ c0,
                float* __restrict__ hn, float* __restrict__ cn,
                float* __restrict__ hA, int hAoff)
{
    int idx = blockIdx.x*256 + threadIdx.x;     // 0..65535
    int b = idx >> 10, k = idx & 1023;
    const float* g = gates + b*4096;
    float ig = bih[k]        + bhh[k];
    float fg = bih[1024 + k] + bhh[1024 + k];
    float gg = bih[2048 + k] + bhh[2048 + k];
    float og = bih[3072 + k] + bhh[3072 + k];
    #pragma unroll
    for (int s = 0; s < SLSTM; ++s) {
        const float* gs = g + s*BB*4096;
        ig += gs[k];
        fg += gs[1024 + k];
        gg += gs[2048 + k];
        og += gs[3072 + k];
    }
    float c = sigmoidf_(fg)*c0[b*HH + k] + sigmoidf_(ig)*tanhf(gg);
    float h = sigmoidf_(og)*tanhf(c);
    cn[b*HH + k] = c;
    hn[b*HH + k] = h;
    hA[b*2048 + hAoff + k] = h;
}

// ---------------- concat reduce + bias + tanh (SCAT=8 partials) ----------------
#define SCAT 8
__global__ __launch_bounds__(256)
void reduce_tanh(const float* __restrict__ P,   // [SCAT][64][1024]
                 const float* __restrict__ bias, float* __restrict__ out)
{
    int idx = blockIdx.x*256 + threadIdx.x;     // 0..65535
    int n = idx & 1023;
    float s = bias[n];
    #pragma unroll
    for (int si = 0; si < SCAT; ++si) s += P[si*65536 + idx];
    out[idx] = tanhf(s);
}

// ---------------- attention: u = attn_W^T v ; c_s = v . attn_b ----------------
__global__ __launch_bounds__(256)
void attn_u_kernel(const float* __restrict__ attn_W, const float* __restrict__ attn_v,
                   const float* __restrict__ attn_b,
                   float* __restrict__ u, float* __restrict__ c_s)
{
    if (blockIdx.x < 32) {
        __shared__ float4 red[16][17];
        int kq = threadIdx.x & 15;      // which float4 of the 64-k chunk
        int hp = threadIdx.x >> 4;      // h stride-group
        int k = blockIdx.x*64 + kq*4;
        float4 s = {0.f,0.f,0.f,0.f};
        for (int h = hp; h < HH; h += 16) {
            float vh = attn_v[h];
            float4 w = *(const float4*)&attn_W[(size_t)h*2048 + k];
            s.x = fmaf(vh, w.x, s.x);
            s.y = fmaf(vh, w.y, s.y);
            s.z = fmaf(vh, w.z, s.z);
            s.w = fmaf(vh, w.w, s.w);
        }
        red[hp][kq] = s;
        __syncthreads();
        if (threadIdx.x < 16) {
            float4 t = {0.f,0.f,0.f,0.f};
            #pragma unroll
            for (int i=0;i<16;++i) {
                float4 r = red[i][threadIdx.x];
                t.x += r.x; t.y += r.y; t.z += r.z; t.w += r.w;
            }
            *(float4*)&u[blockIdx.x*64 + threadIdx.x*4] = t;
        }
    } else {
        __shared__ float red[256];
        float s = 0.f;
        for (int h = threadIdx.x; h < HH; h += 256) s = fmaf(attn_v[h], attn_b[h], s);
        red[threadIdx.x] = s; __syncthreads();
        for (int o = 128; o > 0; o >>= 1) {
            if (threadIdx.x < o) red[threadIdx.x] += red[threadIdx.x + o];
            __syncthreads();
        }
        if (threadIdx.x == 0) *c_s = red[0];
    }
}

// ---------------- d_h[b] = u_h . h_top[b] ----------------
__global__ __launch_bounds__(256)
void dh_kernel(const float* __restrict__ u, const float* __restrict__ Acat3,
               float* __restrict__ d_h)
{
    int b = blockIdx.x;
    __shared__ float red[256];
    float s = 0.f;
    for (int k = threadIdx.x*4; k < HH; k += 1024) {
        float4 uu = *(const float4*)&u[k];
        float4 hh = *(const float4*)&Acat3[b*2048 + 1024 + k];
        s = fmaf(uu.x, hh.x, s); s = fmaf(uu.y, hh.y, s);
        s = fmaf(uu.z, hh.z, s); s = fmaf(uu.w, hh.w, s);
    }
    red[threadIdx.x] = s; __syncthreads();
    for (int o = 128; o > 0; o >>= 1) {
        if (threadIdx.x < o) red[threadIdx.x] += red[threadIdx.x + o];
        __syncthreads();
    }
    if (threadIdx.x == 0) d_h[b] = red[0];
}

// ---------------- scores[b,l] = u_e . enc[l,b,:] + d_h[b] + c_s ----------------
__global__ __launch_bounds__(256)
void scores_kernel(const float* __restrict__ u, const float* __restrict__ enc,
                   const float* __restrict__ d_h, const float* __restrict__ c_s,
                   float* __restrict__ scores)
{
    int w    = blockIdx.x*4 + (threadIdx.x >> 6);   // 0..8191
    int lane = threadIdx.x & 63;
    int b = w >> 7, l = w & 127;
    const float* e = enc + (size_t)(l*BB + b)*HH;
    const float* ue = u + 1024;
    float s = 0.f;
    #pragma unroll
    for (int t = 0; t < 16; ++t)
        s = fmaf(ue[lane + 64*t], e[lane + 64*t], s);
    #pragma unroll
    for (int o = 32; o > 0; o >>= 1) s += __shfl_xor(s, o);
    if (lane == 0) scores[b*SRC + l] = s + d_h[b] + *c_s;
}

// ---------------- softmax over l (128) per b ----------------
__global__ __launch_bounds__(64)
void softmax_kernel(const float* __restrict__ scores, float* __restrict__ w)
{
    int b = blockIdx.x, lane = threadIdx.x;
    float s0 = scores[b*SRC + lane], s1 = scores[b*SRC + 64 + lane];
    float m = fmaxf(s0, s1);
    #pragma unroll
    for (int o = 32; o > 0; o >>= 1) m = fmaxf(m, __shfl_xor(m, o));
    float e0 = expf(s0 - m), e1 = expf(s1 - m);
    float sum = e0 + e1;
    #pragma unroll
    for (int o = 32; o > 0; o >>= 1) sum += __shfl_xor(sum, o);
    float inv = 1.f / sum;
    w[b*SRC + lane]      = e0 * inv;
    w[b*SRC + 64 + lane] = e1 * inv;
}

// ---------------- context[b,h] = sum_l w[b,l] enc[l,b,h] ----------------
__global__ __launch_bounds__(256)
void context_kernel(const float* __restrict__ w, const float* __restrict__ enc,
                    float* __restrict__ Acat3)
{
    int idx = blockIdx.x*256 + threadIdx.x;     // 0..65535
    int b = idx >> 10, h = idx & 1023;
    float s = 0.f;
    #pragma unroll 4
    for (int l = 0; l < SRC; ++l)
        s = fmaf(w[b*SRC + l], enc[(size_t)(l*BB + b)*HH + h], s);
    Acat3[b*2048 + h] = s;
}

// ---------------- log-sum-exp per row of logits (float4) ----------------
__global__ __launch_bounds__(256)
void lse_kernel(const float* __restrict__ logits, float* __restrict__ lse)
{
    int b = blockIdx.x;
    __shared__ float red[256];
    const float4* row = (const float4*)(logits + (size_t)b*VV);  // 8000 float4
    float m = -INFINITY;
    for (int i = threadIdx.x; i < 8000; i += 256) {
        float4 v = row[i];
        m = fmaxf(m, fmaxf(fmaxf(v.x, v.y), fmaxf(v.z, v.w)));
    }
    red[threadIdx.x] = m; __syncthreads();
    for (int o = 128; o > 0; o >>= 1) {
        if (threadIdx.x < o) red[threadIdx.x] = fmaxf(red[threadIdx.x], red[threadIdx.x + o]);
        __syncthreads();
    }
    m = red[0]; __syncthreads();
    float s = 0.f;
    for (int i = threadIdx.x; i < 8000; i += 256) {
        float4 v = row[i];
        s += expf(v.x - m) + expf(v.y - m) + expf(v.z - m) + expf(v.w - m);
    }
    red[threadIdx.x] = s; __syncthreads();
    for (int o = 128; o > 0; o >>= 1) {
        if (threadIdx.x < o) red[threadIdx.x] += red[threadIdx.x + o];
        __syncthreads();
    }
    if (threadIdx.x == 0) lse[b] = m + logf(red[0]);
}

__global__ __launch_bounds__(256)
void sub_kernel(float* __restrict__ logp, const float* __restrict__ lse)
{
    int b = blockIdx.y;
    int i = blockIdx.x*256 + threadIdx.x;       // 0..8191 over 8000 float4
    if (i < 8000) {
        float4* p = (float4*)(logp + (size_t)b*VV);
        float4 v = p[i];
        float l = lse[b];
        v.x -= l; v.y -= l; v.z -= l; v.w -= l;
        p[i] = v;
    }
}

// ================================================================
extern "C" void kernel_launch(void* const* d_in, const int* in_sizes, int n_in,
                              void* d_out, int out_size, void* d_ws, size_t ws_size,
                              hipStream_t stream)
{
    const int*   tokens   = (const int*)  d_in[0];
    const float* h0       = (const float*)d_in[1];
    const float* c0       = (const float*)d_in[2];
    const float* enc      = (const float*)d_in[3];
    const float* emb      = (const float*)d_in[4];
    const float* W_ih     = (const float*)d_in[5];
    const float* W_hh     = (const float*)d_in[6];
    const float* b_ih     = (const float*)d_in[7];
    const float* b_hh     = (const float*)d_in[8];
    const float* attn_W   = (const float*)d_in[9];
    const float* attn_b   = (const float*)d_in[10];
    const float* attn_v   = (const float*)d_in[11];
    const float* concat_W = (const float*)d_in[12];
    const float* concat_b = (const float*)d_in[13];
    const float* out_W    = (const float*)d_in[14];
    const float* out_b    = (const float*)d_in[15];

    float* out  = (float*)d_out;
    float* logp = out;                      // [64, 32000]
    float* h_n  = out + (size_t)BB*VV;      // [2, 64, 1024]
    float* c_n  = h_n + 2*BB*HH;            // [2, 64, 1024]

    // workspace layout (floats)
    float* ws     = (float*)d_ws;
    float* Acat0  = ws;                       // [64, 2048]  = [emb ; h0[0]]
    float* Acat1  = Acat0 + 131072;           // [64, 2048]  = [h1 ; h0[1]]
    float* Acat3  = Acat1 + 131072;           // [64, 2048]  = [context ; h_top]
    float* gates  = Acat3 + 131072;           // [SLSTM=4][64, 4096] partials
    float* catP   = gates + SLSTM*262144;     // [SCAT=8][64, 1024] partials
    float* h_c    = catP  + SCAT*65536;       // [64, 1024]
    float* u      = h_c   + 65536;            // [2048]
    float* c_s    = u     + 2048;             // [1]
    float* d_h    = c_s   + 4;                // [64]
    float* scores = d_h   + 64;               // [64, 128]
    float* attw   = scores+ 8192;             // [64, 128]
    float* lse    = attw  + 8192;             // [64]

    // 1) embedding gather + A_cat prep
    prep_kernel<<<256, 256, 0, stream>>>(tokens, emb, h0, Acat0, Acat1);

    // 2) LSTM layer 0: gates = Acat0 @ [W_ih0 | W_hh0]^T  (split-K S=4, kChunk=512)
    gemm_sk<0><<<dim3(64, SLSTM), 256, 0, stream>>>(Acat0, 2048,
                                      W_ih, W_hh, 1024, 1024,
                                      512, 4096, nullptr, gates);
    lstm_point<<<256, 256, 0, stream>>>(gates, b_ih, b_hh, c0,
                                        h_n, c_n, Acat1, 0);

    // 3) LSTM layer 1
    gemm_sk<0><<<dim3(64, SLSTM), 256, 0, stream>>>(Acat1, 2048,
                                      W_ih + (size_t)4096*1024,
                                      W_hh + (size_t)4096*1024, 1024, 1024,
                                      512, 4096, nullptr, gates);
    lstm_point<<<256, 256, 0, stream>>>(gates, b_ih + 4096, b_hh + 4096, c0 + BB*HH,
                                        h_n + BB*HH, c_n + BB*HH, Acat3, 1024);

    // 4) attention folded vector u = attn_W^T v, scalar c_s = v.b
    attn_u_kernel<<<33, 256, 0, stream>>>(attn_W, attn_v, attn_b, u, c_s);

    // 5) d_h[b] = u_h . h_top[b]
    dh_kernel<<<64, 256, 0, stream>>>(u, Acat3, d_h);

    // 6) scores + softmax + context
    scores_kernel<<<2048, 256, 0, stream>>>(u, enc, d_h, c_s, scores);
    softmax_kernel<<<64, 64, 0, stream>>>(scores, attw);
    context_kernel<<<256, 256, 0, stream>>>(attw, enc, Acat3);

    // 7) concat partials = Acat3 @ concat_W^T  (split-K S=8, kChunk=256)
    gemm_sk<0><<<dim3(16, SCAT), 256, 0, stream>>>(Acat3, 2048,
                                      concat_W, nullptr, 1 << 30, 2048,
                                      256, 1024, nullptr, catP);
    reduce_tanh<<<256, 256, 0, stream>>>(catP, concat_b, h_c);

    // 8) logits = h_c @ out_W^T + out_b  (500 blocks, no split)
    gemm_sk<1><<<dim3(500, 1), 256, 0, stream>>>(h_c, 1024,
                                      out_W, nullptr, 1 << 30, 1024,
                                      1024, VV, out_b, logp);

    // 9) log-softmax
    lse_kernel<<<64, 256, 0, stream>>>(logp, lse);
    sub_kernel<<<dim3(32, 64), 256, 0, stream>>>(logp, lse);
}

// Round 3
// 166.345 us; speedup vs baseline: 3.7617x; 1.5816x over previous
//
#include <hip/hip_runtime.h>
#include <math.h>

#define BB 64
#define HH 1024
#define VV 32000
#define SRC 128

typedef __attribute__((ext_vector_type(8))) __bf16 bf16x8;
typedef __attribute__((ext_vector_type(8))) unsigned short ushort8;
typedef __attribute__((ext_vector_type(4))) float f32x4;

__device__ __forceinline__ float sigmoidf_(float x){ return 1.f/(1.f+expf(-x)); }

__device__ __forceinline__ unsigned short f2bf(float f){
    union { float f; unsigned u; } v; v.f = f;
    unsigned r = v.u + 0x7FFFu + ((v.u >> 16) & 1u);   // round-to-nearest-even
    return (unsigned short)(r >> 16);
}

__device__ __forceinline__ void cvt8(const float4& x, const float4& y, unsigned short* dst){
    ushort8 s;
    s[0]=f2bf(x.x); s[1]=f2bf(x.y); s[2]=f2bf(x.z); s[3]=f2bf(x.w);
    s[4]=f2bf(y.x); s[5]=f2bf(y.y); s[6]=f2bf(y.z); s[7]=f2bf(y.w);
    *(ushort8*)dst = s;
}

// ============ MFMA GEMM: C[64,N] = A[64,K] @ W[N,K]^T (fp32 in, bf16 mfma) ============
// Tile 64M x 128N, BK=64, 256 threads (4 waves, each wave a 32-wide N strip).
// W split into two row-major arrays at global-k K0 (for [W_ih|W_hh]); kChunk % 64 == 0,
// K0 % kChunk == 0. grid = (N/128, S).  EPI: 0 raw partial (+by*64*N), 1 +bias, 2 +bias,tanh
template<int EPI>
__global__ __launch_bounds__(256)
void gemm_bf(const float* __restrict__ A, int lda,
             const float* __restrict__ B0, const float* __restrict__ B1,
             int K0, int ldb, int kChunk, int N,
             const float* __restrict__ bias, float* __restrict__ C)
{
    // padded row stride 72 shorts (144 B): 16B-aligned rows, 2-way-max bank aliasing
    __shared__ __align__(16) unsigned short As[64*72];
    __shared__ __align__(16) unsigned short Bs[128*72];
    const int tid = threadIdx.x;
    const int n0 = blockIdx.x * 128;
    const int kbase = blockIdx.y * kChunk;
    const int nt = kChunk >> 6;

    const int am = tid >> 2, ak = (tid & 3) << 4;   // A stage: row, 16-float k chunk
    const int bn = tid >> 1, bk = (tid & 1) << 5;   // B stage: row, 32-float k chunk

    f32x4 acc[4][2] = {};
    float4 aR[4], bR[8];

    auto loadG = [&](int t){
        int k0g = kbase + (t << 6);
        const float* Ap = A + (size_t)am * lda + k0g + ak;
        #pragma unroll
        for (int i = 0; i < 4; ++i) aR[i] = *(const float4*)(Ap + i*4);
        const float* Bp; int kb;
        if (k0g < K0) { Bp = B0; kb = k0g; } else { Bp = B1; kb = k0g - K0; }
        const float* Bq = Bp + (size_t)(n0 + bn) * ldb + kb + bk;
        #pragma unroll
        for (int i = 0; i < 8; ++i) bR[i] = *(const float4*)(Bq + i*4);
    };
    auto writeL = [&](){
        cvt8(aR[0], aR[1], &As[am*72 + ak]);
        cvt8(aR[2], aR[3], &As[am*72 + ak + 8]);
        #pragma unroll
        for (int h = 0; h < 4; ++h)
            cvt8(bR[h*2], bR[h*2+1], &Bs[bn*72 + bk + h*8]);
    };

    loadG(0);
    writeL();
    __syncthreads();

    const int lane = tid & 63;
    const int wn = (tid >> 6) << 5;           // wave's 32-wide N strip: 0,32,64,96
    const int lr = lane >> 4, lc = lane & 15; // k-group / row-col within fragment

    for (int t = 0; t < nt; ++t) {
        if (t + 1 < nt) loadG(t + 1);         // prefetch next tile (global, fp32)
        #pragma unroll
        for (int ks = 0; ks < 2; ++ks) {      // two K=32 mfma steps per BK=64 tile
            bf16x8 aF[4], bF[2];
            #pragma unroll
            for (int fm = 0; fm < 4; ++fm)
                aF[fm] = *(const bf16x8*)&As[(fm*16 + lc)*72 + ks*32 + lr*8];
            #pragma unroll
            for (int fn = 0; fn < 2; ++fn)
                bF[fn] = *(const bf16x8*)&Bs[(wn + fn*16 + lc)*72 + ks*32 + lr*8];
            #pragma unroll
            for (int fm = 0; fm < 4; ++fm)
                #pragma unroll
                for (int fn = 0; fn < 2; ++fn)
                    acc[fm][fn] = __builtin_amdgcn_mfma_f32_16x16x32_bf16(
                        aF[fm], bF[fn], acc[fm][fn], 0, 0, 0);
        }
        __syncthreads();
        if (t + 1 < nt) { writeL(); __syncthreads(); }
    }

    float* Cp = (EPI == 0) ? (C + (size_t)blockIdx.y * 64 * N) : C;
    #pragma unroll
    for (int fn = 0; fn < 2; ++fn) {
        int n = n0 + wn + fn*16 + lc;
        float bv = (EPI >= 1) ? bias[n] : 0.f;
        #pragma unroll
        for (int fm = 0; fm < 4; ++fm) {
            #pragma unroll
            for (int r = 0; r < 4; ++r) {
                int m = fm*16 + lr*4 + r;     // D: col = lane&15, row = (lane>>4)*4+r
                float v = acc[fm][fn][r] + bv;
                if (EPI == 2) v = tanhf(v);
                Cp[(size_t)m*N + n] = v;
            }
        }
    }
}

// ---------------- embedding gather + A_cat prep ----------------
__global__ __launch_bounds__(256)
void prep_kernel(const int* __restrict__ tokens, const float* __restrict__ emb,
                 const float* __restrict__ h0,
                 float* __restrict__ Acat0, float* __restrict__ Acat1)
{
    int idx = blockIdx.x*256 + threadIdx.x;     // 0..65535
    int b = idx >> 10, k = idx & 1023;
    int tok = tokens[b];
    Acat0[b*2048 + k]        = emb[(size_t)tok*HH + k];
    Acat0[b*2048 + 1024 + k] = h0[b*HH + k];                 // h0[0]
    Acat1[b*2048 + 1024 + k] = h0[BB*HH + b*HH + k];         // h0[1]
}

// ---------------- LSTM pointwise (sums SLSTM=8 split-K partials) ----------------
#define SLSTM 8
__global__ __launch_bounds__(256)
void lstm_point(const float* __restrict__ gates,   // [SLSTM][64][4096]
                const float* __restrict__ bih, const float* __restrict__ bhh,
                const float* __restrict__ c0,
                float* __restrict__ hn, float* __restrict__ cn,
                float* __restrict__ hA, int hAoff)
{
    int idx = blockIdx.x*256 + threadIdx.x;     // 0..65535
    int b = idx >> 10, k = idx & 1023;
    const float* g = gates + b*4096;
    float ig = bih[k]        + bhh[k];
    float fg = bih[1024 + k] + bhh[1024 + k];
    float gg = bih[2048 + k] + bhh[2048 + k];
    float og = bih[3072 + k] + bhh[3072 + k];
    #pragma unroll
    for (int s = 0; s < SLSTM; ++s) {
        const float* gs = g + s*BB*4096;
        ig += gs[k];
        fg += gs[1024 + k];
        gg += gs[2048 + k];
        og += gs[3072 + k];
    }
    float c = sigmoidf_(fg)*c0[b*HH + k] + sigmoidf_(ig)*tanhf(gg);
    float h = sigmoidf_(og)*tanhf(c);
    cn[b*HH + k] = c;
    hn[b*HH + k] = h;
    hA[b*2048 + hAoff + k] = h;
}

// ---------------- concat reduce + bias + tanh (SCAT=8 partials) ----------------
#define SCAT 8
__global__ __launch_bounds__(256)
void reduce_tanh(const float* __restrict__ P,   // [SCAT][64][1024]
                 const float* __restrict__ bias, float* __restrict__ out)
{
    int idx = blockIdx.x*256 + threadIdx.x;     // 0..65535
    int n = idx & 1023;
    float s = bias[n];
    #pragma unroll
    for (int si = 0; si < SCAT; ++si) s += P[si*65536 + idx];
    out[idx] = tanhf(s);
}

// ---------------- attention: u = attn_W^T v ; c_s = v . attn_b ----------------
__global__ __launch_bounds__(256)
void attn_u_kernel(const float* __restrict__ attn_W, const float* __restrict__ attn_v,
                   const float* __restrict__ attn_b,
                   float* __restrict__ u, float* __restrict__ c_s)
{
    if (blockIdx.x < 32) {
        __shared__ float4 red[16][17];
        int kq = threadIdx.x & 15;
        int hp = threadIdx.x >> 4;
        int k = blockIdx.x*64 + kq*4;
        float4 s = {0.f,0.f,0.f,0.f};
        for (int h = hp; h < HH; h += 16) {
            float vh = attn_v[h];
            float4 w = *(const float4*)&attn_W[(size_t)h*2048 + k];
            s.x = fmaf(vh, w.x, s.x);
            s.y = fmaf(vh, w.y, s.y);
            s.z = fmaf(vh, w.z, s.z);
            s.w = fmaf(vh, w.w, s.w);
        }
        red[hp][kq] = s;
        __syncthreads();
        if (threadIdx.x < 16) {
            float4 t = {0.f,0.f,0.f,0.f};
            #pragma unroll
            for (int i=0;i<16;++i) {
                float4 r = red[i][threadIdx.x];
                t.x += r.x; t.y += r.y; t.z += r.z; t.w += r.w;
            }
            *(float4*)&u[blockIdx.x*64 + threadIdx.x*4] = t;
        }
    } else {
        __shared__ float red[256];
        float s = 0.f;
        for (int h = threadIdx.x; h < HH; h += 256) s = fmaf(attn_v[h], attn_b[h], s);
        red[threadIdx.x] = s; __syncthreads();
        for (int o = 128; o > 0; o >>= 1) {
            if (threadIdx.x < o) red[threadIdx.x] += red[threadIdx.x + o];
            __syncthreads();
        }
        if (threadIdx.x == 0) *c_s = red[0];
    }
}

// ---------------- d_h[b] = u_h . h_top[b] ----------------
__global__ __launch_bounds__(256)
void dh_kernel(const float* __restrict__ u, const float* __restrict__ Acat3,
               float* __restrict__ d_h)
{
    int b = blockIdx.x;
    __shared__ float red[256];
    float s = 0.f;
    for (int k = threadIdx.x*4; k < HH; k += 1024) {
        float4 uu = *(const float4*)&u[k];
        float4 hh = *(const float4*)&Acat3[b*2048 + 1024 + k];
        s = fmaf(uu.x, hh.x, s); s = fmaf(uu.y, hh.y, s);
        s = fmaf(uu.z, hh.z, s); s = fmaf(uu.w, hh.w, s);
    }
    red[threadIdx.x] = s; __syncthreads();
    for (int o = 128; o > 0; o >>= 1) {
        if (threadIdx.x < o) red[threadIdx.x] += red[threadIdx.x + o];
        __syncthreads();
    }
    if (threadIdx.x == 0) d_h[b] = red[0];
}

// ---------------- scores[b,l] = u_e . enc[l,b,:] + d_h[b] + c_s ----------------
__global__ __launch_bounds__(256)
void scores_kernel(const float* __restrict__ u, const float* __restrict__ enc,
                   const float* __restrict__ d_h, const float* __restrict__ c_s,
                   float* __restrict__ scores)
{
    int w    = blockIdx.x*4 + (threadIdx.x >> 6);   // 0..8191
    int lane = threadIdx.x & 63;
    int b = w >> 7, l = w & 127;
    const float* e = enc + (size_t)(l*BB + b)*HH;
    const float* ue = u + 1024;
    float s = 0.f;
    #pragma unroll
    for (int t = 0; t < 16; ++t)
        s = fmaf(ue[lane + 64*t], e[lane + 64*t], s);
    #pragma unroll
    for (int o = 32; o > 0; o >>= 1) s += __shfl_xor(s, o);
    if (lane == 0) scores[b*SRC + l] = s + d_h[b] + *c_s;
}

// ---------------- softmax over l (128) per b ----------------
__global__ __launch_bounds__(64)
void softmax_kernel(const float* __restrict__ scores, float* __restrict__ w)
{
    int b = blockIdx.x, lane = threadIdx.x;
    float s0 = scores[b*SRC + lane], s1 = scores[b*SRC + 64 + lane];
    float m = fmaxf(s0, s1);
    #pragma unroll
    for (int o = 32; o > 0; o >>= 1) m = fmaxf(m, __shfl_xor(m, o));
    float e0 = expf(s0 - m), e1 = expf(s1 - m);
    float sum = e0 + e1;
    #pragma unroll
    for (int o = 32; o > 0; o >>= 1) sum += __shfl_xor(sum, o);
    float inv = 1.f / sum;
    w[b*SRC + lane]      = e0 * inv;
    w[b*SRC + 64 + lane] = e1 * inv;
}

// ---------------- context[b,h] = sum_l w[b,l] enc[l,b,h] ----------------
__global__ __launch_bounds__(256)
void context_kernel(const float* __restrict__ w, const float* __restrict__ enc,
                    float* __restrict__ Acat3)
{
    int idx = blockIdx.x*256 + threadIdx.x;     // 0..65535
    int b = idx >> 10, h = idx & 1023;
    float s = 0.f;
    #pragma unroll 4
    for (int l = 0; l < SRC; ++l)
        s = fmaf(w[b*SRC + l], enc[(size_t)(l*BB + b)*HH + h], s);
    Acat3[b*2048 + h] = s;
}

// ---------------- log-sum-exp per row of logits (float4) ----------------
__global__ __launch_bounds__(256)
void lse_kernel(const float* __restrict__ logits, float* __restrict__ lse)
{
    int b = blockIdx.x;
    __shared__ float red[256];
    const float4* row = (const float4*)(logits + (size_t)b*VV);  // 8000 float4
    float m = -INFINITY;
    for (int i = threadIdx.x; i < 8000; i += 256) {
        float4 v = row[i];
        m = fmaxf(m, fmaxf(fmaxf(v.x, v.y), fmaxf(v.z, v.w)));
    }
    red[threadIdx.x] = m; __syncthreads();
    for (int o = 128; o > 0; o >>= 1) {
        if (threadIdx.x < o) red[threadIdx.x] = fmaxf(red[threadIdx.x], red[threadIdx.x + o]);
        __syncthreads();
    }
    m = red[0]; __syncthreads();
    float s = 0.f;
    for (int i = threadIdx.x; i < 8000; i += 256) {
        float4 v = row[i];
        s += expf(v.x - m) + expf(v.y - m) + expf(v.z - m) + expf(v.w - m);
    }
    red[threadIdx.x] = s; __syncthreads();
    for (int o = 128; o > 0; o >>= 1) {
        if (threadIdx.x < o) red[threadIdx.x] += red[threadIdx.x + o];
        __syncthreads();
    }
    if (threadIdx.x == 0) lse[b] = m + logf(red[0]);
}

__global__ __launch_bounds__(256)
void sub_kernel(float* __restrict__ logp, const float* __restrict__ lse)
{
    int b = blockIdx.y;
    int i = blockIdx.x*256 + threadIdx.x;       // over 8000 float4
    if (i < 8000) {
        float4* p = (float4*)(logp + (size_t)b*VV);
        float4 v = p[i];
        float l = lse[b];
        v.x -= l; v.y -= l; v.z -= l; v.w -= l;
        p[i] = v;
    }
}

// ================================================================
extern "C" void kernel_launch(void* const* d_in, const int* in_sizes, int n_in,
                              void* d_out, int out_size, void* d_ws, size_t ws_size,
                              hipStream_t stream)
{
    const int*   tokens   = (const int*)  d_in[0];
    const float* h0       = (const float*)d_in[1];
    const float* c0       = (const float*)d_in[2];
    const float* enc      = (const float*)d_in[3];
    const float* emb      = (const float*)d_in[4];
    const float* W_ih     = (const float*)d_in[5];
    const float* W_hh     = (const float*)d_in[6];
    const float* b_ih     = (const float*)d_in[7];
    const float* b_hh     = (const float*)d_in[8];
    const float* attn_W   = (const float*)d_in[9];
    const float* attn_b   = (const float*)d_in[10];
    const float* attn_v   = (const float*)d_in[11];
    const float* concat_W = (const float*)d_in[12];
    const float* concat_b = (const float*)d_in[13];
    const float* out_W    = (const float*)d_in[14];
    const float* out_b    = (const float*)d_in[15];

    float* out  = (float*)d_out;
    float* logp = out;                      // [64, 32000]
    float* h_n  = out + (size_t)BB*VV;      // [2, 64, 1024]
    float* c_n  = h_n + 2*BB*HH;            // [2, 64, 1024]

    // workspace layout (floats)
    float* ws     = (float*)d_ws;
    float* Acat0  = ws;                       // [64, 2048]  = [emb ; h0[0]]
    float* Acat1  = Acat0 + 131072;           // [64, 2048]  = [h1 ; h0[1]]
    float* Acat3  = Acat1 + 131072;           // [64, 2048]  = [context ; h_top]
    float* gates  = Acat3 + 131072;           // [SLSTM=8][64, 4096] partials
    float* catP   = gates;                    // [SCAT=8][64, 1024] (aliases gates; disjoint lifetime)
    float* h_c    = gates + SLSTM*262144;     // [64, 1024]
    float* u      = h_c   + 65536;            // [2048]
    float* c_s    = u     + 2048;             // [1]
    float* d_h    = c_s   + 4;                // [64]
    float* scores = d_h   + 64;               // [64, 128]
    float* attw   = scores+ 8192;             // [64, 128]
    float* lse    = attw  + 8192;             // [64]

    // 1) embedding gather + A_cat prep
    prep_kernel<<<256, 256, 0, stream>>>(tokens, emb, h0, Acat0, Acat1);

    // 2) LSTM layer 0: gates = Acat0 @ [W_ih0 | W_hh0]^T  (split-K S=8, kChunk=256)
    gemm_bf<0><<<dim3(32, SLSTM), 256, 0, stream>>>(Acat0, 2048,
                                      W_ih, W_hh, 1024, 1024,
                                      256, 4096, nullptr, gates);
    lstm_point<<<256, 256, 0, stream>>>(gates, b_ih, b_hh, c0,
                                        h_n, c_n, Acat1, 0);

    // 3) LSTM layer 1
    gemm_bf<0><<<dim3(32, SLSTM), 256, 0, stream>>>(Acat1, 2048,
                                      W_ih + (size_t)4096*1024,
                                      W_hh + (size_t)4096*1024, 1024, 1024,
                                      256, 4096, nullptr, gates);
    lstm_point<<<256, 256, 0, stream>>>(gates, b_ih + 4096, b_hh + 4096, c0 + BB*HH,
                                        h_n + BB*HH, c_n + BB*HH, Acat3, 1024);

    // 4) attention folded vector u = attn_W^T v, scalar c_s = v.b
    attn_u_kernel<<<33, 256, 0, stream>>>(attn_W, attn_v, attn_b, u, c_s);

    // 5) d_h[b] = u_h . h_top[b]
    dh_kernel<<<64, 256, 0, stream>>>(u, Acat3, d_h);

    // 6) scores + softmax + context
    scores_kernel<<<2048, 256, 0, stream>>>(u, enc, d_h, c_s, scores);
    softmax_kernel<<<64, 64, 0, stream>>>(scores, attw);
    context_kernel<<<256, 256, 0, stream>>>(attw, enc, Acat3);

    // 7) concat partials = Acat3 @ concat_W^T  (split-K S=8, kChunk=256)
    gemm_bf<0><<<dim3(8, SCAT), 256, 0, stream>>>(Acat3, 2048,
                                      concat_W, nullptr, 1 << 30, 2048,
                                      256, 1024, nullptr, catP);
    reduce_tanh<<<256, 256, 0, stream>>>(catP, concat_b, h_c);

    // 8) logits = h_c @ out_W^T + out_b  (250 blocks, no split)
    gemm_bf<1><<<dim3(250, 1), 256, 0, stream>>>(h_c, 1024,
                                      out_W, nullptr, 1 << 30, 1024,
                                      1024, VV, out_b, logp);

    // 9) log-softmax
    lse_kernel<<<64, 256, 0, stream>>>(logp, lse);
    sub_kernel<<<dim3(32, 64), 256, 0, stream>>>(logp, lse);
}

// Round 4
// 166.284 us; speedup vs baseline: 3.7631x; 1.0004x over previous
//
#include <hip/hip_runtime.h>
#include <math.h>

#define BB 64
#define HH 1024
#define VV 32000
#define SRC 128

typedef __attribute__((ext_vector_type(8))) __bf16 bf16x8;
typedef __attribute__((ext_vector_type(8))) unsigned short ushort8;
typedef __attribute__((ext_vector_type(4))) float f32x4;

__device__ __forceinline__ float sigmoidf_(float x){ return 1.f/(1.f+expf(-x)); }

__device__ __forceinline__ unsigned short f2bf(float f){
    union { float f; unsigned u; } v; v.f = f;
    unsigned r = v.u + 0x7FFFu + ((v.u >> 16) & 1u);   // round-to-nearest-even
    return (unsigned short)(r >> 16);
}

__device__ __forceinline__ void cvt8(const float4& x, const float4& y, unsigned short* dst){
    ushort8 s;
    s[0]=f2bf(x.x); s[1]=f2bf(x.y); s[2]=f2bf(x.z); s[3]=f2bf(x.w);
    s[4]=f2bf(y.x); s[5]=f2bf(y.y); s[6]=f2bf(y.z); s[7]=f2bf(y.w);
    *(ushort8*)dst = s;
}

// ============ MFMA GEMM: C[64,N] = A[64,K] @ W[N,K]^T (fp32 in, bf16 mfma) ============
// Tile 64M x 128N, BK=64, 256 threads (4 waves, each wave a 32-wide N strip).
// W split into two row-major arrays at global-k K0 (for [W_ih|W_hh]); kChunk % 64 == 0,
// K0 % kChunk == 0. grid = (N/128, S).  EPI: 0 raw partial (+by*64*N), 1 +bias, 2 +bias,tanh
template<int EPI>
__global__ __launch_bounds__(256)
void gemm_bf(const float* __restrict__ A, int lda,
             const float* __restrict__ B0, const float* __restrict__ B1,
             int K0, int ldb, int kChunk, int N,
             const float* __restrict__ bias, float* __restrict__ C)
{
    // padded row stride 72 shorts (144 B): 16B-aligned rows, 2-way-max bank aliasing
    __shared__ __align__(16) unsigned short As[64*72];
    __shared__ __align__(16) unsigned short Bs[128*72];
    const int tid = threadIdx.x;
    const int n0 = blockIdx.x * 128;
    const int kbase = blockIdx.y * kChunk;
    const int nt = kChunk >> 6;

    const int am = tid >> 2, ak = (tid & 3) << 4;   // A stage: row, 16-float k chunk
    const int bn = tid >> 1, bk = (tid & 1) << 5;   // B stage: row, 32-float k chunk

    f32x4 acc[4][2] = {};
    float4 aR[4], bR[8];

    auto loadG = [&](int t){
        int k0g = kbase + (t << 6);
        const float* Ap = A + (size_t)am * lda + k0g + ak;
        #pragma unroll
        for (int i = 0; i < 4; ++i) aR[i] = *(const float4*)(Ap + i*4);
        const float* Bp; int kb;
        if (k0g < K0) { Bp = B0; kb = k0g; } else { Bp = B1; kb = k0g - K0; }
        const float* Bq = Bp + (size_t)(n0 + bn) * ldb + kb + bk;
        #pragma unroll
        for (int i = 0; i < 8; ++i) bR[i] = *(const float4*)(Bq + i*4);
    };
    auto writeL = [&](){
        cvt8(aR[0], aR[1], &As[am*72 + ak]);
        cvt8(aR[2], aR[3], &As[am*72 + ak + 8]);
        #pragma unroll
        for (int h = 0; h < 4; ++h)
            cvt8(bR[h*2], bR[h*2+1], &Bs[bn*72 + bk + h*8]);
    };

    loadG(0);
    writeL();
    __syncthreads();

    const int lane = tid & 63;
    const int wn = (tid >> 6) << 5;           // wave's 32-wide N strip: 0,32,64,96
    const int lr = lane >> 4, lc = lane & 15; // k-group / row-col within fragment

    for (int t = 0; t < nt; ++t) {
        if (t + 1 < nt) loadG(t + 1);         // prefetch next tile (global, fp32)
        #pragma unroll
        for (int ks = 0; ks < 2; ++ks) {      // two K=32 mfma steps per BK=64 tile
            bf16x8 aF[4], bF[2];
            #pragma unroll
            for (int fm = 0; fm < 4; ++fm)
                aF[fm] = *(const bf16x8*)&As[(fm*16 + lc)*72 + ks*32 + lr*8];
            #pragma unroll
            for (int fn = 0; fn < 2; ++fn)
                bF[fn] = *(const bf16x8*)&Bs[(wn + fn*16 + lc)*72 + ks*32 + lr*8];
            #pragma unroll
            for (int fm = 0; fm < 4; ++fm)
                #pragma unroll
                for (int fn = 0; fn < 2; ++fn)
                    acc[fm][fn] = __builtin_amdgcn_mfma_f32_16x16x32_bf16(
                        aF[fm], bF[fn], acc[fm][fn], 0, 0, 0);
        }
        __syncthreads();
        if (t + 1 < nt) { writeL(); __syncthreads(); }
    }

    float* Cp = (EPI == 0) ? (C + (size_t)blockIdx.y * 64 * N) : C;
    #pragma unroll
    for (int fn = 0; fn < 2; ++fn) {
        int n = n0 + wn + fn*16 + lc;
        float bv = (EPI >= 1) ? bias[n] : 0.f;
        #pragma unroll
        for (int fm = 0; fm < 4; ++fm) {
            #pragma unroll
            for (int r = 0; r < 4; ++r) {
                int m = fm*16 + lr*4 + r;     // D: col = lane&15, row = (lane>>4)*4+r
                float v = acc[fm][fn][r] + bv;
                if (EPI == 2) v = tanhf(v);
                Cp[(size_t)m*N + n] = v;
            }
        }
    }
}

// ---------------- embedding gather + A_cat prep ----------------
__global__ __launch_bounds__(256)
void prep_kernel(const int* __restrict__ tokens, const float* __restrict__ emb,
                 const float* __restrict__ h0,
                 float* __restrict__ Acat0, float* __restrict__ Acat1)
{
    int idx = blockIdx.x*256 + threadIdx.x;     // 0..65535
    int b = idx >> 10, k = idx & 1023;
    int tok = tokens[b];
    Acat0[b*2048 + k]        = emb[(size_t)tok*HH + k];
    Acat0[b*2048 + 1024 + k] = h0[b*HH + k];                 // h0[0]
    Acat1[b*2048 + 1024 + k] = h0[BB*HH + b*HH + k];         // h0[1]
}

// ---------------- LSTM pointwise (sums SLSTM=8 split-K partials) ----------------
#define SLSTM 8
__global__ __launch_bounds__(256)
void lstm_point(const float* __restrict__ gates,   // [SLSTM][64][4096]
                const float* __restrict__ bih, const float* __restrict__ bhh,
                const float* __restrict__ c0,
                float* __restrict__ hn, float* __restrict__ cn,
                float* __restrict__ hA, int hAoff)
{
    int idx = blockIdx.x*256 + threadIdx.x;     // 0..65535
    int b = idx >> 10, k = idx & 1023;
    const float* g = gates + b*4096;
    float ig = bih[k]        + bhh[k];
    float fg = bih[1024 + k] + bhh[1024 + k];
    float gg = bih[2048 + k] + bhh[2048 + k];
    float og = bih[3072 + k] + bhh[3072 + k];
    #pragma unroll
    for (int s = 0; s < SLSTM; ++s) {
        const float* gs = g + s*BB*4096;
        ig += gs[k];
        fg += gs[1024 + k];
        gg += gs[2048 + k];
        og += gs[3072 + k];
    }
    float c = sigmoidf_(fg)*c0[b*HH + k] + sigmoidf_(ig)*tanhf(gg);
    float h = sigmoidf_(og)*tanhf(c);
    cn[b*HH + k] = c;
    hn[b*HH + k] = h;
    hA[b*2048 + hAoff + k] = h;
}

// ---------------- concat reduce + bias + tanh (SCAT=8 partials) ----------------
#define SCAT 8
__global__ __launch_bounds__(256)
void reduce_tanh(const float* __restrict__ P,   // [SCAT][64][1024]
                 const float* __restrict__ bias, float* __restrict__ out)
{
    int idx = blockIdx.x*256 + threadIdx.x;     // 0..65535
    int n = idx & 1023;
    float s = bias[n];
    #pragma unroll
    for (int si = 0; si < SCAT; ++si) s += P[si*65536 + idx];
    out[idx] = tanhf(s);
}

// ---------------- attention: u = attn_W^T v ; c_s = v . attn_b ----------------
__global__ __launch_bounds__(256)
void attn_u_kernel(const float* __restrict__ attn_W, const float* __restrict__ attn_v,
                   const float* __restrict__ attn_b,
                   float* __restrict__ u, float* __restrict__ c_s)
{
    if (blockIdx.x < 32) {
        __shared__ float4 red[16][17];
        int kq = threadIdx.x & 15;
        int hp = threadIdx.x >> 4;
        int k = blockIdx.x*64 + kq*4;
        float4 s = {0.f,0.f,0.f,0.f};
        for (int h = hp; h < HH; h += 16) {
            float vh = attn_v[h];
            float4 w = *(const float4*)&attn_W[(size_t)h*2048 + k];
            s.x = fmaf(vh, w.x, s.x);
            s.y = fmaf(vh, w.y, s.y);
            s.z = fmaf(vh, w.z, s.z);
            s.w = fmaf(vh, w.w, s.w);
        }
        red[hp][kq] = s;
        __syncthreads();
        if (threadIdx.x < 16) {
            float4 t = {0.f,0.f,0.f,0.f};
            #pragma unroll
            for (int i=0;i<16;++i) {
                float4 r = red[i][threadIdx.x];
                t.x += r.x; t.y += r.y; t.z += r.z; t.w += r.w;
            }
            *(float4*)&u[blockIdx.x*64 + threadIdx.x*4] = t;
        }
    } else {
        __shared__ float red[256];
        float s = 0.f;
        for (int h = threadIdx.x; h < HH; h += 256) s = fmaf(attn_v[h], attn_b[h], s);
        red[threadIdx.x] = s; __syncthreads();
        for (int o = 128; o > 0; o >>= 1) {
            if (threadIdx.x < o) red[threadIdx.x] += red[threadIdx.x + o];
            __syncthreads();
        }
        if (threadIdx.x == 0) *c_s = red[0];
    }
}

// ---------------- d_h[b] = u_h . h_top[b] ----------------
__global__ __launch_bounds__(256)
void dh_kernel(const float* __restrict__ u, const float* __restrict__ Acat3,
               float* __restrict__ d_h)
{
    int b = blockIdx.x;
    __shared__ float red[256];
    float s = 0.f;
    for (int k = threadIdx.x*4; k < HH; k += 1024) {
        float4 uu = *(const float4*)&u[k];
        float4 hh = *(const float4*)&Acat3[b*2048 + 1024 + k];
        s = fmaf(uu.x, hh.x, s); s = fmaf(uu.y, hh.y, s);
        s = fmaf(uu.z, hh.z, s); s = fmaf(uu.w, hh.w, s);
    }
    red[threadIdx.x] = s; __syncthreads();
    for (int o = 128; o > 0; o >>= 1) {
        if (threadIdx.x < o) red[threadIdx.x] += red[threadIdx.x + o];
        __syncthreads();
    }
    if (threadIdx.x == 0) d_h[b] = red[0];
}

// ---------------- scores[b,l] = u_e . enc[l,b,:] + d_h[b] + c_s ----------------
__global__ __launch_bounds__(256)
void scores_kernel(const float* __restrict__ u, const float* __restrict__ enc,
                   const float* __restrict__ d_h, const float* __restrict__ c_s,
                   float* __restrict__ scores)
{
    int w    = blockIdx.x*4 + (threadIdx.x >> 6);   // 0..8191
    int lane = threadIdx.x & 63;
    int b = w >> 7, l = w & 127;
    const float* e = enc + (size_t)(l*BB + b)*HH;
    const float* ue = u + 1024;
    float s = 0.f;
    #pragma unroll
    for (int t = 0; t < 16; ++t)
        s = fmaf(ue[lane + 64*t], e[lane + 64*t], s);
    #pragma unroll
    for (int o = 32; o > 0; o >>= 1) s += __shfl_xor(s, o);
    if (lane == 0) scores[b*SRC + l] = s + d_h[b] + *c_s;
}

// ---------------- softmax over l (128) per b ----------------
__global__ __launch_bounds__(64)
void softmax_kernel(const float* __restrict__ scores, float* __restrict__ w)
{
    int b = blockIdx.x, lane = threadIdx.x;
    float s0 = scores[b*SRC + lane], s1 = scores[b*SRC + 64 + lane];
    float m = fmaxf(s0, s1);
    #pragma unroll
    for (int o = 32; o > 0; o >>= 1) m = fmaxf(m, __shfl_xor(m, o));
    float e0 = expf(s0 - m), e1 = expf(s1 - m);
    float sum = e0 + e1;
    #pragma unroll
    for (int o = 32; o > 0; o >>= 1) sum += __shfl_xor(sum, o);
    float inv = 1.f / sum;
    w[b*SRC + lane]      = e0 * inv;
    w[b*SRC + 64 + lane] = e1 * inv;
}

// ---------------- context[b,h] = sum_l w[b,l] enc[l,b,h] ----------------
__global__ __launch_bounds__(256)
void context_kernel(const float* __restrict__ w, const float* __restrict__ enc,
                    float* __restrict__ Acat3)
{
    int idx = blockIdx.x*256 + threadIdx.x;     // 0..65535
    int b = idx >> 10, h = idx & 1023;
    float s = 0.f;
    #pragma unroll 4
    for (int l = 0; l < SRC; ++l)
        s = fmaf(w[b*SRC + l], enc[(size_t)(l*BB + b)*HH + h], s);
    Acat3[b*2048 + h] = s;
}

// ---------------- log-sum-exp per row of logits (float4) ----------------
__global__ __launch_bounds__(256)
void lse_kernel(const float* __restrict__ logits, float* __restrict__ lse)
{
    int b = blockIdx.x;
    __shared__ float red[256];
    const float4* row = (const float4*)(logits + (size_t)b*VV);  // 8000 float4
    float m = -INFINITY;
    for (int i = threadIdx.x; i < 8000; i += 256) {
        float4 v = row[i];
        m = fmaxf(m, fmaxf(fmaxf(v.x, v.y), fmaxf(v.z, v.w)));
    }
    red[threadIdx.x] = m; __syncthreads();
    for (int o = 128; o > 0; o >>= 1) {
        if (threadIdx.x < o) red[threadIdx.x] = fmaxf(red[threadIdx.x], red[threadIdx.x + o]);
        __syncthreads();
    }
    m = red[0]; __syncthreads();
    float s = 0.f;
    for (int i = threadIdx.x; i < 8000; i += 256) {
        float4 v = row[i];
        s += expf(v.x - m) + expf(v.y - m) + expf(v.z - m) + expf(v.w - m);
    }
    red[threadIdx.x] = s; __syncthreads();
    for (int o = 128; o > 0; o >>= 1) {
        if (threadIdx.x < o) red[threadIdx.x] += red[threadIdx.x + o];
        __syncthreads();
    }
    if (threadIdx.x == 0) lse[b] = m + logf(red[0]);
}

__global__ __launch_bounds__(256)
void sub_kernel(float* __restrict__ logp, const float* __restrict__ lse)
{
    int b = blockIdx.y;
    int i = blockIdx.x*256 + threadIdx.x;       // over 8000 float4
    if (i < 8000) {
        float4* p = (float4*)(logp + (size_t)b*VV);
        float4 v = p[i];
        float l = lse[b];
        v.x -= l; v.y -= l; v.z -= l; v.w -= l;
        p[i] = v;
    }
}

// ================================================================
extern "C" void kernel_launch(void* const* d_in, const int* in_sizes, int n_in,
                              void* d_out, int out_size, void* d_ws, size_t ws_size,
                              hipStream_t stream)
{
    const int*   tokens   = (const int*)  d_in[0];
    const float* h0       = (const float*)d_in[1];
    const float* c0       = (const float*)d_in[2];
    const float* enc      = (const float*)d_in[3];
    const float* emb      = (const float*)d_in[4];
    const float* W_ih     = (const float*)d_in[5];
    const float* W_hh     = (const float*)d_in[6];
    const float* b_ih     = (const float*)d_in[7];
    const float* b_hh     = (const float*)d_in[8];
    const float* attn_W   = (const float*)d_in[9];
    const float* attn_b   = (const float*)d_in[10];
    const float* attn_v   = (const float*)d_in[11];
    const float* concat_W = (const float*)d_in[12];
    const float* concat_b = (const float*)d_in[13];
    const float* out_W    = (const float*)d_in[14];
    const float* out_b    = (const float*)d_in[15];

    float* out  = (float*)d_out;
    float* logp = out;                      // [64, 32000]
    float* h_n  = out + (size_t)BB*VV;      // [2, 64, 1024]
    float* c_n  = h_n + 2*BB*HH;            // [2, 64, 1024]

    // workspace layout (floats)
    float* ws     = (float*)d_ws;
    float* Acat0  = ws;                       // [64, 2048]  = [emb ; h0[0]]
    float* Acat1  = Acat0 + 131072;           // [64, 2048]  = [h1 ; h0[1]]
    float* Acat3  = Acat1 + 131072;           // [64, 2048]  = [context ; h_top]
    float* gates  = Acat3 + 131072;           // [SLSTM=8][64, 4096] partials
    float* catP   = gates;                    // [SCAT=8][64, 1024] (aliases gates; disjoint lifetime)
    float* h_c    = gates + SLSTM*262144;     // [64, 1024]
    float* u      = h_c   + 65536;            // [2048]
    float* c_s    = u     + 2048;             // [1]
    float* d_h    = c_s   + 4;                // [64]
    float* scores = d_h   + 64;               // [64, 128]
    float* attw   = scores+ 8192;             // [64, 128]
    float* lse    = attw  + 8192;             // [64]

    // 1) embedding gather + A_cat prep
    prep_kernel<<<256, 256, 0, stream>>>(tokens, emb, h0, Acat0, Acat1);

    // 2) LSTM layer 0: gates = Acat0 @ [W_ih0 | W_hh0]^T  (split-K S=8, kChunk=256)
    gemm_bf<0><<<dim3(32, SLSTM), 256, 0, stream>>>(Acat0, 2048,
                                      W_ih, W_hh, 1024, 1024,
                                      256, 4096, nullptr, gates);
    lstm_point<<<256, 256, 0, stream>>>(gates, b_ih, b_hh, c0,
                                        h_n, c_n, Acat1, 0);

    // 3) LSTM layer 1
    gemm_bf<0><<<dim3(32, SLSTM), 256, 0, stream>>>(Acat1, 2048,
                                      W_ih + (size_t)4096*1024,
                                      W_hh + (size_t)4096*1024, 1024, 1024,
                                      256, 4096, nullptr, gates);
    lstm_point<<<256, 256, 0, stream>>>(gates, b_ih + 4096, b_hh + 4096, c0 + BB*HH,
                                        h_n + BB*HH, c_n + BB*HH, Acat3, 1024);

    // 4) attention folded vector u = attn_W^T v, scalar c_s = v.b
    attn_u_kernel<<<33, 256, 0, stream>>>(attn_W, attn_v, attn_b, u, c_s);

    // 5) d_h[b] = u_h . h_top[b]
    dh_kernel<<<64, 256, 0, stream>>>(u, Acat3, d_h);

    // 6) scores + softmax + context
    scores_kernel<<<2048, 256, 0, stream>>>(u, enc, d_h, c_s, scores);
    softmax_kernel<<<64, 64, 0, stream>>>(scores, attw);
    context_kernel<<<256, 256, 0, stream>>>(attw, enc, Acat3);

    // 7) concat partials = Acat3 @ concat_W^T  (split-K S=8, kChunk=256)
    gemm_bf<0><<<dim3(8, SCAT), 256, 0, stream>>>(Acat3, 2048,
                                      concat_W, nullptr, 1 << 30, 2048,
                                      256, 1024, nullptr, catP);
    reduce_tanh<<<256, 256, 0, stream>>>(catP, concat_b, h_c);

    // 8) logits = h_c @ out_W^T + out_b  (250 blocks, no split)
    gemm_bf<1><<<dim3(250, 1), 256, 0, stream>>>(h_c, 1024,
                                      out_W, nullptr, 1 << 30, 1024,
                                      1024, VV, out_b, logp);

    // 9) log-softmax
    lse_kernel<<<64, 256, 0, stream>>>(logp, lse);
    sub_kernel<<<dim3(32, 64), 256, 0, stream>>>(logp, lse);
}

// Round 5
// 161.131 us; speedup vs baseline: 3.8834x; 1.0320x over previous
//
#include <hip/hip_runtime.h>
#include <math.h>

#define BB 64
#define HH 1024
#define VV 32000
#define SRC 128

typedef __attribute__((ext_vector_type(8))) __bf16 bf16x8;
typedef __attribute__((ext_vector_type(8))) unsigned short ushort8;
typedef __attribute__((ext_vector_type(4))) float f32x4;

__device__ __forceinline__ float sigmoidf_(float x){ return 1.f/(1.f+expf(-x)); }

__device__ __forceinline__ unsigned short f2bf(float f){
    union { float f; unsigned u; } v; v.f = f;
    unsigned r = v.u + 0x7FFFu + ((v.u >> 16) & 1u);   // round-to-nearest-even
    return (unsigned short)(r >> 16);
}

__device__ __forceinline__ void cvt8(const float4& x, const float4& y, unsigned short* dst){
    ushort8 s;
    s[0]=f2bf(x.x); s[1]=f2bf(x.y); s[2]=f2bf(x.z); s[3]=f2bf(x.w);
    s[4]=f2bf(y.x); s[5]=f2bf(y.y); s[6]=f2bf(y.z); s[7]=f2bf(y.w);
    *(ushort8*)dst = s;
}

// ============ MFMA GEMM: C[64,N] = A[64,K] @ W[N,K]^T (fp32 in, bf16 mfma) ============
// Tile 64M x 128N, BK=64, 256 threads (4 waves, each wave a 32-wide N strip).
// W split into two row-major arrays at global-k K0 (for [W_ih|W_hh]); kChunk % 64 == 0,
// K0 % kChunk == 0. grid = (N/128, S).  EPI: 0 raw partial (+by*64*N), 1 +bias, 2 +bias,tanh
template<int EPI>
__global__ __launch_bounds__(256)
void gemm_bf(const float* __restrict__ A, int lda,
             const float* __restrict__ B0, const float* __restrict__ B1,
             int K0, int ldb, int kChunk, int N,
             const float* __restrict__ bias, float* __restrict__ C)
{
    // padded row stride 72 shorts (144 B): 16B-aligned rows, 2-way-max bank aliasing
    __shared__ __align__(16) unsigned short As[64*72];
    __shared__ __align__(16) unsigned short Bs[128*72];
    const int tid = threadIdx.x;
    const int n0 = blockIdx.x * 128;
    const int kbase = blockIdx.y * kChunk;
    const int nt = kChunk >> 6;

    const int am = tid >> 2, ak = (tid & 3) << 4;   // A stage: row, 16-float k chunk
    const int bn = tid >> 1, bk = (tid & 1) << 5;   // B stage: row, 32-float k chunk

    f32x4 acc[4][2] = {};
    float4 aR[4], bR[8];

    auto loadG = [&](int t){
        int k0g = kbase + (t << 6);
        const float* Ap = A + (size_t)am * lda + k0g + ak;
        #pragma unroll
        for (int i = 0; i < 4; ++i) aR[i] = *(const float4*)(Ap + i*4);
        const float* Bp; int kb;
        if (k0g < K0) { Bp = B0; kb = k0g; } else { Bp = B1; kb = k0g - K0; }
        const float* Bq = Bp + (size_t)(n0 + bn) * ldb + kb + bk;
        #pragma unroll
        for (int i = 0; i < 8; ++i) bR[i] = *(const float4*)(Bq + i*4);
    };
    auto writeL = [&](){
        cvt8(aR[0], aR[1], &As[am*72 + ak]);
        cvt8(aR[2], aR[3], &As[am*72 + ak + 8]);
        #pragma unroll
        for (int h = 0; h < 4; ++h)
            cvt8(bR[h*2], bR[h*2+1], &Bs[bn*72 + bk + h*8]);
    };

    loadG(0);
    writeL();
    __syncthreads();

    const int lane = tid & 63;
    const int wn = (tid >> 6) << 5;           // wave's 32-wide N strip: 0,32,64,96
    const int lr = lane >> 4, lc = lane & 15; // k-group / row-col within fragment

    for (int t = 0; t < nt; ++t) {
        if (t + 1 < nt) loadG(t + 1);         // prefetch next tile (global, fp32)
        #pragma unroll
        for (int ks = 0; ks < 2; ++ks) {      // two K=32 mfma steps per BK=64 tile
            bf16x8 aF[4], bF[2];
            #pragma unroll
            for (int fm = 0; fm < 4; ++fm)
                aF[fm] = *(const bf16x8*)&As[(fm*16 + lc)*72 + ks*32 + lr*8];
            #pragma unroll
            for (int fn = 0; fn < 2; ++fn)
                bF[fn] = *(const bf16x8*)&Bs[(wn + fn*16 + lc)*72 + ks*32 + lr*8];
            #pragma unroll
            for (int fm = 0; fm < 4; ++fm)
                #pragma unroll
                for (int fn = 0; fn < 2; ++fn)
                    acc[fm][fn] = __builtin_amdgcn_mfma_f32_16x16x32_bf16(
                        aF[fm], bF[fn], acc[fm][fn], 0, 0, 0);
        }
        __syncthreads();
        if (t + 1 < nt) { writeL(); __syncthreads(); }
    }

    float* Cp = (EPI == 0) ? (C + (size_t)blockIdx.y * 64 * N) : C;
    #pragma unroll
    for (int fn = 0; fn < 2; ++fn) {
        int n = n0 + wn + fn*16 + lc;
        float bv = (EPI >= 1) ? bias[n] : 0.f;
        #pragma unroll
        for (int fm = 0; fm < 4; ++fm) {
            #pragma unroll
            for (int r = 0; r < 4; ++r) {
                int m = fm*16 + lr*4 + r;     // D: col = lane&15, row = (lane>>4)*4+r
                float v = acc[fm][fn][r] + bv;
                if (EPI == 2) v = tanhf(v);
                Cp[(size_t)m*N + n] = v;
            }
        }
    }
}

// ---------------- embedding gather + A_cat prep ----------------
__global__ __launch_bounds__(256)
void prep_kernel(const int* __restrict__ tokens, const float* __restrict__ emb,
                 const float* __restrict__ h0,
                 float* __restrict__ Acat0, float* __restrict__ Acat1)
{
    int idx = blockIdx.x*256 + threadIdx.x;     // 0..65535
    int b = idx >> 10, k = idx & 1023;
    int tok = tokens[b];
    Acat0[b*2048 + k]        = emb[(size_t)tok*HH + k];
    Acat0[b*2048 + 1024 + k] = h0[b*HH + k];                 // h0[0]
    Acat1[b*2048 + 1024 + k] = h0[BB*HH + b*HH + k];         // h0[1]
}

// ---------------- LSTM pointwise (sums SLSTM=8 split-K partials) ----------------
#define SLSTM 8
__global__ __launch_bounds__(256)
void lstm_point(const float* __restrict__ gates,   // [SLSTM][64][4096]
                const float* __restrict__ bih, const float* __restrict__ bhh,
                const float* __restrict__ c0,
                float* __restrict__ hn, float* __restrict__ cn,
                float* __restrict__ hA, int hAoff)
{
    int idx = blockIdx.x*256 + threadIdx.x;     // 0..65535
    int b = idx >> 10, k = idx & 1023;
    const float* g = gates + b*4096;
    float ig = bih[k]        + bhh[k];
    float fg = bih[1024 + k] + bhh[1024 + k];
    float gg = bih[2048 + k] + bhh[2048 + k];
    float og = bih[3072 + k] + bhh[3072 + k];
    #pragma unroll
    for (int s = 0; s < SLSTM; ++s) {
        const float* gs = g + s*BB*4096;
        ig += gs[k];
        fg += gs[1024 + k];
        gg += gs[2048 + k];
        og += gs[3072 + k];
    }
    float c = sigmoidf_(fg)*c0[b*HH + k] + sigmoidf_(ig)*tanhf(gg);
    float h = sigmoidf_(og)*tanhf(c);
    cn[b*HH + k] = c;
    hn[b*HH + k] = h;
    hA[b*2048 + hAoff + k] = h;
}

// ---------------- concat reduce + bias + tanh (SCAT=8 partials) ----------------
#define SCAT 8
__global__ __launch_bounds__(256)
void reduce_tanh(const float* __restrict__ P,   // [SCAT][64][1024]
                 const float* __restrict__ bias, float* __restrict__ out)
{
    int idx = blockIdx.x*256 + threadIdx.x;     // 0..65535
    int n = idx & 1023;
    float s = bias[n];
    #pragma unroll
    for (int si = 0; si < SCAT; ++si) s += P[si*65536 + idx];
    out[idx] = tanhf(s);
}

// ---------------- attention: u = attn_W^T v ; c_s = v . attn_b ----------------
__global__ __launch_bounds__(256)
void attn_u_kernel(const float* __restrict__ attn_W, const float* __restrict__ attn_v,
                   const float* __restrict__ attn_b,
                   float* __restrict__ u, float* __restrict__ c_s)
{
    if (blockIdx.x < 32) {
        __shared__ float4 red[16][17];
        int kq = threadIdx.x & 15;
        int hp = threadIdx.x >> 4;
        int k = blockIdx.x*64 + kq*4;
        float4 s = {0.f,0.f,0.f,0.f};
        for (int h = hp; h < HH; h += 16) {
            float vh = attn_v[h];
            float4 w = *(const float4*)&attn_W[(size_t)h*2048 + k];
            s.x = fmaf(vh, w.x, s.x);
            s.y = fmaf(vh, w.y, s.y);
            s.z = fmaf(vh, w.z, s.z);
            s.w = fmaf(vh, w.w, s.w);
        }
        red[hp][kq] = s;
        __syncthreads();
        if (threadIdx.x < 16) {
            float4 t = {0.f,0.f,0.f,0.f};
            #pragma unroll
            for (int i=0;i<16;++i) {
                float4 r = red[i][threadIdx.x];
                t.x += r.x; t.y += r.y; t.z += r.z; t.w += r.w;
            }
            *(float4*)&u[blockIdx.x*64 + threadIdx.x*4] = t;
        }
    } else {
        __shared__ float red[256];
        float s = 0.f;
        for (int h = threadIdx.x; h < HH; h += 256) s = fmaf(attn_v[h], attn_b[h], s);
        red[threadIdx.x] = s; __syncthreads();
        for (int o = 128; o > 0; o >>= 1) {
            if (threadIdx.x < o) red[threadIdx.x] += red[threadIdx.x + o];
            __syncthreads();
        }
        if (threadIdx.x == 0) *c_s = red[0];
    }
}

// ---------------- d_h[b] = u_h . h_top[b] ----------------
__global__ __launch_bounds__(256)
void dh_kernel(const float* __restrict__ u, const float* __restrict__ Acat3,
               float* __restrict__ d_h)
{
    int b = blockIdx.x;
    __shared__ float red[256];
    float s = 0.f;
    for (int k = threadIdx.x*4; k < HH; k += 1024) {
        float4 uu = *(const float4*)&u[k];
        float4 hh = *(const float4*)&Acat3[b*2048 + 1024 + k];
        s = fmaf(uu.x, hh.x, s); s = fmaf(uu.y, hh.y, s);
        s = fmaf(uu.z, hh.z, s); s = fmaf(uu.w, hh.w, s);
    }
    red[threadIdx.x] = s; __syncthreads();
    for (int o = 128; o > 0; o >>= 1) {
        if (threadIdx.x < o) red[threadIdx.x] += red[threadIdx.x + o];
        __syncthreads();
    }
    if (threadIdx.x == 0) d_h[b] = red[0];
}

// ---------------- scores[b,l] = u_e . enc[l,b,:] + d_h[b] + c_s ----------------
__global__ __launch_bounds__(256)
void scores_kernel(const float* __restrict__ u, const float* __restrict__ enc,
                   const float* __restrict__ d_h, const float* __restrict__ c_s,
                   float* __restrict__ scores)
{
    int w    = blockIdx.x*4 + (threadIdx.x >> 6);   // 0..8191
    int lane = threadIdx.x & 63;
    int b = w >> 7, l = w & 127;
    const float* e = enc + (size_t)(l*BB + b)*HH;
    const float* ue = u + 1024;
    float s = 0.f;
    #pragma unroll
    for (int t = 0; t < 16; ++t)
        s = fmaf(ue[lane + 64*t], e[lane + 64*t], s);
    #pragma unroll
    for (int o = 32; o > 0; o >>= 1) s += __shfl_xor(s, o);
    if (lane == 0) scores[b*SRC + l] = s + d_h[b] + *c_s;
}

// ---------------- softmax over l (128) per b ----------------
__global__ __launch_bounds__(64)
void softmax_kernel(const float* __restrict__ scores, float* __restrict__ w)
{
    int b = blockIdx.x, lane = threadIdx.x;
    float s0 = scores[b*SRC + lane], s1 = scores[b*SRC + 64 + lane];
    float m = fmaxf(s0, s1);
    #pragma unroll
    for (int o = 32; o > 0; o >>= 1) m = fmaxf(m, __shfl_xor(m, o));
    float e0 = expf(s0 - m), e1 = expf(s1 - m);
    float sum = e0 + e1;
    #pragma unroll
    for (int o = 32; o > 0; o >>= 1) sum += __shfl_xor(sum, o);
    float inv = 1.f / sum;
    w[b*SRC + lane]      = e0 * inv;
    w[b*SRC + 64 + lane] = e1 * inv;
}

// ---------------- context[b,h] = sum_l w[b,l] enc[l,b,h] ----------------
__global__ __launch_bounds__(256)
void context_kernel(const float* __restrict__ w, const float* __restrict__ enc,
                    float* __restrict__ Acat3)
{
    int idx = blockIdx.x*256 + threadIdx.x;     // 0..65535
    int b = idx >> 10, h = idx & 1023;
    float s = 0.f;
    #pragma unroll 4
    for (int l = 0; l < SRC; ++l)
        s = fmaf(w[b*SRC + l], enc[(size_t)(l*BB + b)*HH + h], s);
    Acat3[b*2048 + h] = s;
}

// ---------------- log-sum-exp per row of logits (float4) ----------------
__global__ __launch_bounds__(256)
void lse_kernel(const float* __restrict__ logits, float* __restrict__ lse)
{
    int b = blockIdx.x;
    __shared__ float red[256];
    const float4* row = (const float4*)(logits + (size_t)b*VV);  // 8000 float4
    float m = -INFINITY;
    for (int i = threadIdx.x; i < 8000; i += 256) {
        float4 v = row[i];
        m = fmaxf(m, fmaxf(fmaxf(v.x, v.y), fmaxf(v.z, v.w)));
    }
    red[threadIdx.x] = m; __syncthreads();
    for (int o = 128; o > 0; o >>= 1) {
        if (threadIdx.x < o) red[threadIdx.x] = fmaxf(red[threadIdx.x], red[threadIdx.x + o]);
        __syncthreads();
    }
    m = red[0]; __syncthreads();
    float s = 0.f;
    for (int i = threadIdx.x; i < 8000; i += 256) {
        float4 v = row[i];
        s += expf(v.x - m) + expf(v.y - m) + expf(v.z - m) + expf(v.w - m);
    }
    red[threadIdx.x] = s; __syncthreads();
    for (int o = 128; o > 0; o >>= 1) {
        if (threadIdx.x < o) red[threadIdx.x] += red[threadIdx.x + o];
        __syncthreads();
    }
    if (threadIdx.x == 0) lse[b] = m + logf(red[0]);
}

__global__ __launch_bounds__(256)
void sub_kernel(float* __restrict__ logp, const float* __restrict__ lse)
{
    int b = blockIdx.y;
    int i = blockIdx.x*256 + threadIdx.x;       // over 8000 float4
    if (i < 8000) {
        float4* p = (float4*)(logp + (size_t)b*VV);
        float4 v = p[i];
        float l = lse[b];
        v.x -= l; v.y -= l; v.z -= l; v.w -= l;
        p[i] = v;
    }
}

// ================================================================
extern "C" void kernel_launch(void* const* d_in, const int* in_sizes, int n_in,
                              void* d_out, int out_size, void* d_ws, size_t ws_size,
                              hipStream_t stream)
{
    const int*   tokens   = (const int*)  d_in[0];
    const float* h0       = (const float*)d_in[1];
    const float* c0       = (const float*)d_in[2];
    const float* enc      = (const float*)d_in[3];
    const float* emb      = (const float*)d_in[4];
    const float* W_ih     = (const float*)d_in[5];
    const float* W_hh     = (const float*)d_in[6];
    const float* b_ih     = (const float*)d_in[7];
    const float* b_hh     = (const float*)d_in[8];
    const float* attn_W   = (const float*)d_in[9];
    const float* attn_b   = (const float*)d_in[10];
    const float* attn_v   = (const float*)d_in[11];
    const float* concat_W = (const float*)d_in[12];
    const float* concat_b = (const float*)d_in[13];
    const float* out_W    = (const float*)d_in[14];
    const float* out_b    = (const float*)d_in[15];

    float* out  = (float*)d_out;
    float* logp = out;                      // [64, 32000]
    float* h_n  = out + (size_t)BB*VV;      // [2, 64, 1024]
    float* c_n  = h_n + 2*BB*HH;            // [2, 64, 1024]

    // workspace layout (floats)
    float* ws     = (float*)d_ws;
    float* Acat0  = ws;                       // [64, 2048]  = [emb ; h0[0]]
    float* Acat1  = Acat0 + 131072;           // [64, 2048]  = [h1 ; h0[1]]
    float* Acat3  = Acat1 + 131072;           // [64, 2048]  = [context ; h_top]
    float* gates  = Acat3 + 131072;           // [SLSTM=8][64, 4096] partials
    float* catP   = gates;                    // [SCAT=8][64, 1024] (aliases gates; disjoint lifetime)
    float* h_c    = gates + SLSTM*262144;     // [64, 1024]
    float* u      = h_c   + 65536;            // [2048]
    float* c_s    = u     + 2048;             // [1]
    float* d_h    = c_s   + 4;                // [64]
    float* scores = d_h   + 64;               // [64, 128]
    float* attw   = scores+ 8192;             // [64, 128]
    float* lse    = attw  + 8192;             // [64]

    // 1) embedding gather + A_cat prep
    prep_kernel<<<256, 256, 0, stream>>>(tokens, emb, h0, Acat0, Acat1);

    // 2) LSTM layer 0: gates = Acat0 @ [W_ih0 | W_hh0]^T  (split-K S=8, kChunk=256)
    gemm_bf<0><<<dim3(32, SLSTM), 256, 0, stream>>>(Acat0, 2048,
                                      W_ih, W_hh, 1024, 1024,
                                      256, 4096, nullptr, gates);
    lstm_point<<<256, 256, 0, stream>>>(gates, b_ih, b_hh, c0,
                                        h_n, c_n, Acat1, 0);

    // 3) LSTM layer 1
    gemm_bf<0><<<dim3(32, SLSTM), 256, 0, stream>>>(Acat1, 2048,
                                      W_ih + (size_t)4096*1024,
                                      W_hh + (size_t)4096*1024, 1024, 1024,
                                      256, 4096, nullptr, gates);
    lstm_point<<<256, 256, 0, stream>>>(gates, b_ih + 4096, b_hh + 4096, c0 + BB*HH,
                                        h_n + BB*HH, c_n + BB*HH, Acat3, 1024);

    // 4) attention folded vector u = attn_W^T v, scalar c_s = v.b
    attn_u_kernel<<<33, 256, 0, stream>>>(attn_W, attn_v, attn_b, u, c_s);

    // 5) d_h[b] = u_h . h_top[b]
    dh_kernel<<<64, 256, 0, stream>>>(u, Acat3, d_h);

    // 6) scores + softmax + context
    scores_kernel<<<2048, 256, 0, stream>>>(u, enc, d_h, c_s, scores);
    softmax_kernel<<<64, 64, 0, stream>>>(scores, attw);
    context_kernel<<<256, 256, 0, stream>>>(attw, enc, Acat3);

    // 7) concat partials = Acat3 @ concat_W^T  (split-K S=8, kChunk=256)
    gemm_bf<0><<<dim3(8, SCAT), 256, 0, stream>>>(Acat3, 2048,
                                      concat_W, nullptr, 1 << 30, 2048,
                                      256, 1024, nullptr, catP);
    reduce_tanh<<<256, 256, 0, stream>>>(catP, concat_b, h_c);

    // 8) logits = h_c @ out_W^T + out_b  (250 blocks, no split)
    gemm_bf<1><<<dim3(250, 1), 256, 0, stream>>>(h_c, 1024,
                                      out_W, nullptr, 1 << 30, 1024,
                                      1024, VV, out_b, logp);

    // 9) log-softmax
    lse_kernel<<<64, 256, 0, stream>>>(logp, lse);
    sub_kernel<<<dim3(32, 64), 256, 0, stream>>>(logp, lse);
}